// Round 1
// baseline (138.823 us; speedup 1.0000x reference)
//
#include <hip/hip_runtime.h>

#define GRID_N 192
constexpr int NROWS = GRID_N * GRID_N;   // 36864 rows of 192 floats (h contiguous)
constexpr int RPB   = 16;                // rows per block (4 rows per wave)
constexpr int NBLK  = NROWS / RPB;       // 2304 blocks

// ws accumulator layout (floats):
//   [0..191]    hD   (sum of D over l,w per h)
//   [192..383]  hM
//   [384..575]  lD   (sum of D over w,h per l)
//   [576..767]  lM
//   [768..959]  wD   (sum of D over l,h per w)
//   [960..1151] wM
constexpr int ACC_FLOATS = 1152;

__global__ __launch_bounds__(256) void slice_main(
    const float* __restrict__ vx,  const float* __restrict__ vy,
    const float* __restrict__ vz,  const float* __restrict__ p,
    const float* __restrict__ mask,
    const float* __restrict__ rvx, const float* __restrict__ rvy,
    const float* __restrict__ rvz, const float* __restrict__ rp,
    float* __restrict__ acc)
{
    const int tid  = threadIdx.x;
    const int wv   = tid >> 6;
    const int lane = tid & 63;
    const bool act = lane < 48;       // 48 lanes x float4 = 192 floats = one row
    const int hb   = lane << 2;       // h base owned by this lane

    // per-lane h-column accumulators (h = hb..hb+3), summed across rows
    float cD0=0.f,cD1=0.f,cD2=0.f,cD3=0.f;
    float cM0=0.f,cM1=0.f,cM2=0.f,cM3=0.f;

    const int row0 = blockIdx.x * RPB + wv * (RPB / 4);
#pragma unroll
    for (int r = 0; r < RPB / 4; ++r) {
        const int row = row0 + r;
        float d0=0.f,d1=0.f,d2=0.f,d3=0.f;
        float m0=0.f,m1=0.f,m2=0.f,m3=0.f;
        if (act) {
            const size_t base = (size_t)row * GRID_N + hb;
            float4 a, b;
            a = *(const float4*)(rvx + base); b = *(const float4*)(vx + base);
            d0 = a.x-b.x; d1 = a.y-b.y; d2 = a.z-b.z; d3 = a.w-b.w;
            a = *(const float4*)(rvy + base); b = *(const float4*)(vy + base);
            d0 += a.x-b.x; d1 += a.y-b.y; d2 += a.z-b.z; d3 += a.w-b.w;
            a = *(const float4*)(rvz + base); b = *(const float4*)(vz + base);
            d0 += a.x-b.x; d1 += a.y-b.y; d2 += a.z-b.z; d3 += a.w-b.w;
            a = *(const float4*)(rp  + base); b = *(const float4*)(p  + base);
            d0 += a.x-b.x; d1 += a.y-b.y; d2 += a.z-b.z; d3 += a.w-b.w;
            a = *(const float4*)(mask + base);
            m0 = a.x; m1 = a.y; m2 = a.z; m3 = a.w;
        }
        cD0 += d0; cD1 += d1; cD2 += d2; cD3 += d3;
        cM0 += m0; cM1 += m1; cM2 += m2; cM3 += m3;

        // row sums (over h) -> lD[l], wD[w] (and mask counterparts)
        float rd = (d0 + d1) + (d2 + d3);
        float rm = (m0 + m1) + (m2 + m3);
#pragma unroll
        for (int off = 32; off; off >>= 1) {
            rd += __shfl_xor(rd, off);
            rm += __shfl_xor(rm, off);
        }
        if (lane == 0) {
            const int l = row / GRID_N;
            const int w = row - l * GRID_N;
            atomicAdd(&acc[384 + l], rd);
            atomicAdd(&acc[576 + l], rm);
            atomicAdd(&acc[768 + w], rd);
            atomicAdd(&acc[960 + w], rm);
        }
    }

    // block-level combine of per-lane h-column partials, then one atomic per h
    __shared__ float sD[4][192];
    __shared__ float sM[4][192];
    if (act) {
        sD[wv][hb+0]=cD0; sD[wv][hb+1]=cD1; sD[wv][hb+2]=cD2; sD[wv][hb+3]=cD3;
        sM[wv][hb+0]=cM0; sM[wv][hb+1]=cM1; sM[wv][hb+2]=cM2; sM[wv][hb+3]=cM3;
    }
    __syncthreads();
    if (tid < 192) {
        float d = (sD[0][tid] + sD[1][tid]) + (sD[2][tid] + sD[3][tid]);
        float m = (sM[0][tid] + sM[1][tid]) + (sM[2][tid] + sM[3][tid]);
        atomicAdd(&acc[tid],       d);
        atomicAdd(&acc[192 + tid], m);
    }
}

__global__ __launch_bounds__(192) void slice_final(const float* __restrict__ acc,
                                                   float* __restrict__ out)
{
    const int t = threadIdx.x;  // 0..191, one slice index per thread
    double term = (double)acc[384 + t] / (double)acc[576 + t]   // lossl terms
                + (double)acc[768 + t] / (double)acc[960 + t]   // lossw terms
                + (double)acc[t]       / (double)acc[192 + t];  // lossh terms
#pragma unroll
    for (int off = 32; off; off >>= 1) term += __shfl_xor(term, off);
    __shared__ double s[3];
    if ((t & 63) == 0) s[t >> 6] = term;
    __syncthreads();
    if (t == 0) out[0] = (float)((s[0] + s[1] + s[2]) * (1.0 / 192.0));
}

extern "C" void kernel_launch(void* const* d_in, const int* in_sizes, int n_in,
                              void* d_out, int out_size, void* d_ws, size_t ws_size,
                              hipStream_t stream)
{
    const float* vx   = (const float*)d_in[0];
    const float* vy   = (const float*)d_in[1];
    const float* vz   = (const float*)d_in[2];
    const float* p    = (const float*)d_in[3];
    const float* mask = (const float*)d_in[4];
    const float* rvx  = (const float*)d_in[5];
    const float* rvy  = (const float*)d_in[6];
    const float* rvz  = (const float*)d_in[7];
    const float* rp   = (const float*)d_in[8];

    float* acc = (float*)d_ws;
    hipMemsetAsync(acc, 0, ACC_FLOATS * sizeof(float), stream);

    slice_main<<<NBLK, 256, 0, stream>>>(vx, vy, vz, p, mask,
                                         rvx, rvy, rvz, rp, acc);
    slice_final<<<1, 192, 0, stream>>>(acc, (float*)d_out);
}

// Round 2
// 68.724 us; speedup vs baseline: 2.0200x; 2.0200x over previous
//
#include <hip/hip_runtime.h>

#define GRID_N 192
constexpr int NROWS = GRID_N * GRID_N;    // 36864 rows of 192 floats (h contiguous)
constexpr int RPB   = 48;                 // rows per block (12 per wave); block = one l, 48 consecutive w
constexpr int NBLK  = NROWS / RPB;        // 768 blocks = 192 l * 4 blocks-per-l
constexpr int RPW   = RPB / 4;            // 12 rows per wave

// Replicated accumulator: R copies of 1152 floats, replica = blockIdx % R.
//   [0..191]    hD   [192..383]  hM
//   [384..575]  lD   [576..767]  lM
//   [768..959]  wD   [960..1151] wM
constexpr int ACC_FLOATS = 1152;

__global__ __launch_bounds__(256) void slice_main(
    const float* __restrict__ vx,  const float* __restrict__ vy,
    const float* __restrict__ vz,  const float* __restrict__ p,
    const float* __restrict__ mask,
    const float* __restrict__ rvx, const float* __restrict__ rvy,
    const float* __restrict__ rvz, const float* __restrict__ rp,
    float* __restrict__ acc, int R)
{
    const int tid  = threadIdx.x;
    const int wv   = tid >> 6;
    const int lane = tid & 63;
    const bool act = lane < 48;           // 48 lanes x float4 = one 192-float row
    const int hb   = lane << 2;

    float* __restrict__ racc = acc + (size_t)(blockIdx.x % R) * ACC_FLOATS;

    const int l  = blockIdx.x >> 2;               // 4 blocks per l
    const int w0 = (blockIdx.x & 3) * RPB;        // 48 consecutive w per block
    const int rowbase = l * GRID_N + w0 + wv * RPW;

    __shared__ float sD[4][192];
    __shared__ float sM[4][192];
    __shared__ float sRowD[RPB];
    __shared__ float sRowM[RPB];

    float cD0=0.f,cD1=0.f,cD2=0.f,cD3=0.f;
    float cM0=0.f,cM1=0.f,cM2=0.f,cM3=0.f;

#pragma unroll 4
    for (int r = 0; r < RPW; ++r) {
        const int row = rowbase + r;
        float d0=0.f,d1=0.f,d2=0.f,d3=0.f;
        float m0=0.f,m1=0.f,m2=0.f,m3=0.f;
        if (act) {
            const size_t base = (size_t)row * GRID_N + hb;
            float4 a, b;
            a = *(const float4*)(rvx + base); b = *(const float4*)(vx + base);
            d0 = a.x-b.x; d1 = a.y-b.y; d2 = a.z-b.z; d3 = a.w-b.w;
            a = *(const float4*)(rvy + base); b = *(const float4*)(vy + base);
            d0 += a.x-b.x; d1 += a.y-b.y; d2 += a.z-b.z; d3 += a.w-b.w;
            a = *(const float4*)(rvz + base); b = *(const float4*)(vz + base);
            d0 += a.x-b.x; d1 += a.y-b.y; d2 += a.z-b.z; d3 += a.w-b.w;
            a = *(const float4*)(rp  + base); b = *(const float4*)(p  + base);
            d0 += a.x-b.x; d1 += a.y-b.y; d2 += a.z-b.z; d3 += a.w-b.w;
            a = *(const float4*)(mask + base);
            m0 = a.x; m1 = a.y; m2 = a.z; m3 = a.w;
        }
        cD0 += d0; cD1 += d1; cD2 += d2; cD3 += d3;
        cM0 += m0; cM1 += m1; cM2 += m2; cM3 += m3;

        // row sum over h -> one slot per row (w = w0 + wv*RPW + r)
        float rd = (d0 + d1) + (d2 + d3);
        float rm = (m0 + m1) + (m2 + m3);
#pragma unroll
        for (int off = 32; off; off >>= 1) {
            rd += __shfl_xor(rd, off);
            rm += __shfl_xor(rm, off);
        }
        if (lane == 0) {
            sRowD[wv * RPW + r] = rd;
            sRowM[wv * RPW + r] = rm;
        }
    }

    if (act) {
        sD[wv][hb+0]=cD0; sD[wv][hb+1]=cD1; sD[wv][hb+2]=cD2; sD[wv][hb+3]=cD3;
        sM[wv][hb+0]=cM0; sM[wv][hb+1]=cM1; sM[wv][hb+2]=cM2; sM[wv][hb+3]=cM3;
    }
    __syncthreads();

    // h-columns: one atomic per h per block, into this block's replica
    if (tid < 192) {
        float d = (sD[0][tid] + sD[1][tid]) + (sD[2][tid] + sD[3][tid]);
        float m = (sM[0][tid] + sM[1][tid]) + (sM[2][tid] + sM[3][tid]);
        atomicAdd(&racc[tid],       d);
        atomicAdd(&racc[192 + tid], m);
    }
    // w slots: 48 per block (block-aggregated row sums)
    if (tid < RPB) {
        atomicAdd(&racc[768 + w0 + tid], sRowD[tid]);
        atomicAdd(&racc[960 + w0 + tid], sRowM[tid]);
    }
    // l: reduce the 48 row sums in wave 0, 2 atomics per block
    if (tid < 64) {
        float vd = (tid < RPB) ? sRowD[tid] : 0.f;
        float vm = (tid < RPB) ? sRowM[tid] : 0.f;
#pragma unroll
        for (int off = 32; off; off >>= 1) {
            vd += __shfl_xor(vd, off);
            vm += __shfl_xor(vm, off);
        }
        if (tid == 0) {
            atomicAdd(&racc[384 + l], vd);
            atomicAdd(&racc[576 + l], vm);
        }
    }
}

__global__ __launch_bounds__(192) void slice_final(const float* __restrict__ acc,
                                                   float* __restrict__ out, int R)
{
    const int t = threadIdx.x;  // 0..191, one slice index per thread
    double hD=0, hM=0, lD=0, lM=0, wD=0, wM=0;
    for (int r = 0; r < R; ++r) {
        const float* a = acc + (size_t)r * ACC_FLOATS;
        hD += a[t];       hM += a[192 + t];
        lD += a[384 + t]; lM += a[576 + t];
        wD += a[768 + t]; wM += a[960 + t];
    }
    double term = lD / lM + wD / wM + hD / hM;
#pragma unroll
    for (int off = 32; off; off >>= 1) term += __shfl_xor(term, off);
    __shared__ double s[3];
    if ((t & 63) == 0) s[t >> 6] = term;
    __syncthreads();
    if (t == 0) out[0] = (float)((s[0] + s[1] + s[2]) * (1.0 / 192.0));
}

extern "C" void kernel_launch(void* const* d_in, const int* in_sizes, int n_in,
                              void* d_out, int out_size, void* d_ws, size_t ws_size,
                              hipStream_t stream)
{
    const float* vx   = (const float*)d_in[0];
    const float* vy   = (const float*)d_in[1];
    const float* vz   = (const float*)d_in[2];
    const float* p    = (const float*)d_in[3];
    const float* mask = (const float*)d_in[4];
    const float* rvx  = (const float*)d_in[5];
    const float* rvy  = (const float*)d_in[6];
    const float* rvz  = (const float*)d_in[7];
    const float* rp   = (const float*)d_in[8];

    int R = (int)(ws_size / (ACC_FLOATS * sizeof(float)));
    if (R < 1)  R = 1;
    if (R > 64) R = 64;

    float* acc = (float*)d_ws;
    hipMemsetAsync(acc, 0, (size_t)R * ACC_FLOATS * sizeof(float), stream);

    slice_main<<<NBLK, 256, 0, stream>>>(vx, vy, vz, p, mask,
                                         rvx, rvy, rvz, rp, acc, R);
    slice_final<<<1, 192, 0, stream>>>(acc, (float*)d_out, R);
}